// Round 1
// baseline (122.312 us; speedup 1.0000x reference)
//
#include <hip/hip_runtime.h>
#include <hip/hip_bf16.h>

#define B_  64
#define T_  2048
#define E_  512
#define Q_  1024
#define A_  128
#define C_  32
#define KW_ 31

using bf16x8 = __attribute__((ext_vector_type(8))) short;
using f32x4  = __attribute__((ext_vector_type(4))) float;

__device__ __forceinline__ short f2bf(float f) {
  union { float f; unsigned u; } x; x.f = f;
  unsigned r = x.u + 0x7fffu + ((x.u >> 16) & 1u);   // RNE
  return (short)(r >> 16);
}

__device__ __forceinline__ float fast_tanh(float x) {
  float xc = fminf(fmaxf(x, -15.f), 15.f);
  float e2 = __expf(2.f * xc);                 // v_exp path
  return 1.f - 2.f * __builtin_amdgcn_rcpf(e2 + 1.f);
}

// ---------------- prep: conv(prev_att)->locb bf16 [B,T,32]; q2 = dh@Wq + convb@Wloc;
// ---------------- Wk, Wloc pre-swizzled into MFMA B-fragment order (bf16)
__global__ __launch_bounds__(256) void prep_kernel(
    const float* __restrict__ prev, const float* __restrict__ conv_w,
    const float* __restrict__ dh, const float* __restrict__ Wq,
    const float* __restrict__ conv_b, const float* __restrict__ Wloc,
    const float* __restrict__ Wk,
    unsigned short* __restrict__ locb, unsigned short* __restrict__ wkf,
    unsigned short* __restrict__ wlocf, float* __restrict__ q2)
{
  int blk = blockIdx.x;
  int tid = threadIdx.x;
  if (blk < 512) {
    // depthwise-ish conv: each thread computes one t, 32 output channels
    __shared__ float sp[286];        // 256 + 30 halo
    __shared__ float scw[31][32];    // [tap][channel], broadcast reads
    int bb = blk >> 3;
    int t0 = (blk & 7) << 8;
    for (int i = tid; i < 286; i += 256) {
      int t = t0 - 15 + i;
      sp[i] = (t >= 0 && t < T_) ? prev[bb * T_ + t] : 0.f;
    }
    for (int i = tid; i < 992; i += 256) {
      int j = i >> 5, c = i & 31;    // 31*32
      scw[j][c] = conv_w[c * KW_ + j];
    }
    __syncthreads();
    float acc[32];
    #pragma unroll
    for (int c = 0; c < 32; ++c) acc[c] = 0.f;
    for (int j = 0; j < 31; ++j) {
      float p = sp[tid + j];
      #pragma unroll
      for (int c = 0; c < 32; ++c) acc[c] += p * scw[j][c];
    }
    unsigned short* dst = locb + (size_t)(bb * T_ + t0 + tid) * 32;
    #pragma unroll
    for (int g = 0; g < 4; ++g) {
      bf16x8 o;
      #pragma unroll
      for (int j = 0; j < 8; ++j) o[j] = f2bf(acc[g * 8 + j]);
      *(bf16x8*)(dst + g * 8) = o;
    }
  } else if (blk < 576) {
    // q2[b,a] = sum_k dh[b,k]*Wq[k,a] + sum_c conv_b[c]*Wloc[c,a]
    int bb = blk - 512;
    if (tid < 128) {
      int a = tid;
      float s0 = 0, s1 = 0, s2 = 0, s3 = 0;
      const float* dhr = dh + bb * Q_;
      for (int k = 0; k < Q_; k += 4) {
        s0 += dhr[k + 0] * Wq[(k + 0) * A_ + a];
        s1 += dhr[k + 1] * Wq[(k + 1) * A_ + a];
        s2 += dhr[k + 2] * Wq[(k + 2) * A_ + a];
        s3 += dhr[k + 3] * Wq[(k + 3) * A_ + a];
      }
      float s = (s0 + s1) + (s2 + s3);
      for (int c = 0; c < 32; ++c) s += conv_b[c] * Wloc[c * A_ + a];
      q2[bb * A_ + a] = s;
    }
  } else if (blk < 608) {
    // Wk -> B-fragment order: group g=(kstep,ntile); elem j: k=ks*32+(lane>>4)*8+j, n=nt*16+(lane&15)
    int wave = tid >> 6, lane = tid & 63;
    int g = (blk - 576) * 4 + wave;          // 0..127
    int ks = g >> 3, nt = g & 7;
    int lg = lane >> 4, lr = lane & 15;
    bf16x8 o;
    #pragma unroll
    for (int j = 0; j < 8; ++j)
      o[j] = f2bf(Wk[(ks * 32 + lg * 8 + j) * A_ + nt * 16 + lr]);
    *(bf16x8*)(wkf + ((size_t)g * 64 + lane) * 8) = o;
  } else {
    // Wloc -> B-fragment order (single K-step of 32)
    int wave = tid >> 6, lane = tid & 63;
    int g = (blk - 608) * 4 + wave;          // 0..7
    int lg = lane >> 4, lr = lane & 15;
    bf16x8 o;
    #pragma unroll
    for (int j = 0; j < 8; ++j)
      o[j] = f2bf(Wloc[(lg * 8 + j) * A_ + g * 16 + lr]);
    *(bf16x8*)(wlocf + ((size_t)g * 64 + lane) * 8) = o;
  }
}

// ---------------- main: energy[b,t] = v . tanh(enc@Wk + q2[b] + loc@Wloc), no keys materialization
// 4 waves/block, each wave: 16 rows x 128 cols, A-frags streamed from global (fp32->bf16)
__global__ __launch_bounds__(256) void energy_kernel(
    const float* __restrict__ enc, const unsigned short* __restrict__ locb,
    const unsigned short* __restrict__ wkf, const unsigned short* __restrict__ wlocf,
    const float* __restrict__ q2, const float* __restrict__ vvec,
    float* __restrict__ energy)
{
  int wave = threadIdx.x >> 6;
  int lane = threadIdx.x & 63;
  int m0 = blockIdx.x * 64 + wave * 16;   // flattened b*T+t row base of this wave
  int b  = m0 >> 11;                      // /T (64 | T so no straddle)
  int lg = lane >> 4, lr = lane & 15;

  // A-frag: row = lane&15, k = (lane>>4)*8 + j  -> 32B contiguous per lane in enc
  const float* encRow = enc + (size_t)(m0 + lr) * E_ + lg * 8;

  f32x4 acc[8];
  #pragma unroll
  for (int i = 0; i < 8; ++i) acc[i] = (f32x4){0.f, 0.f, 0.f, 0.f};

  const unsigned short* wkl = wkf + (size_t)lane * 8;
  for (int ks = 0; ks < 16; ++ks) {
    float4 a0 = *(const float4*)(encRow + ks * 32);
    float4 a1 = *(const float4*)(encRow + ks * 32 + 4);
    bf16x8 af;
    af[0] = f2bf(a0.x); af[1] = f2bf(a0.y); af[2] = f2bf(a0.z); af[3] = f2bf(a0.w);
    af[4] = f2bf(a1.x); af[5] = f2bf(a1.y); af[6] = f2bf(a1.z); af[7] = f2bf(a1.w);
    #pragma unroll
    for (int nt = 0; nt < 8; ++nt) {
      bf16x8 bf = *(const bf16x8*)(wkl + (size_t)(ks * 8 + nt) * 64 * 8);
      acc[nt] = __builtin_amdgcn_mfma_f32_16x16x32_bf16(af, bf, acc[nt], 0, 0, 0);
    }
  }
  { // location term: one extra K=32 MFMA step (K = conv channels)
    bf16x8 af = *(const bf16x8*)(locb + (size_t)(m0 + lr) * 32 + lg * 8);
    #pragma unroll
    for (int nt = 0; nt < 8; ++nt) {
      bf16x8 bf = *(const bf16x8*)(wlocf + ((size_t)nt * 64 + lane) * 8);
      acc[nt] = __builtin_amdgcn_mfma_f32_16x16x32_bf16(af, bf, acc[nt], 0, 0, 0);
    }
  }
  // D layout: row = m0 + lg*4 + r, col = nt*16 + lr
  float p0 = 0, p1 = 0, p2 = 0, p3 = 0;
  const float* q2r = q2 + b * A_;
  #pragma unroll
  for (int nt = 0; nt < 8; ++nt) {
    int n = nt * 16 + lr;
    float qv = q2r[n];
    float vv = vvec[n];
    p0 += fast_tanh(acc[nt][0] + qv) * vv;
    p1 += fast_tanh(acc[nt][1] + qv) * vv;
    p2 += fast_tanh(acc[nt][2] + qv) * vv;
    p3 += fast_tanh(acc[nt][3] + qv) * vv;
  }
  #pragma unroll
  for (int off = 1; off < 16; off <<= 1) {   // reduce across the 16 lanes of group lg
    p0 += __shfl_xor(p0, off, 64);
    p1 += __shfl_xor(p1, off, 64);
    p2 += __shfl_xor(p2, off, 64);
    p3 += __shfl_xor(p3, off, 64);
  }
  if (lr == 0) {
    float4 o = make_float4(p0, p1, p2, p3);  // rows m0+lg*4 .. +3 contiguous
    *(float4*)(energy + m0 + lg * 4) = o;
  }
}

// ---------------- softmax over T per row b, in-place on d_out
__global__ __launch_bounds__(256) void softmax_kernel(float* __restrict__ out)
{
  int bb = blockIdx.x;
  int tid = threadIdx.x;
  float* row = out + (size_t)bb * T_;
  float vals[8];
  float m = -1e30f;
  #pragma unroll
  for (int i = 0; i < 8; ++i) { vals[i] = row[tid + i * 256]; m = fmaxf(m, vals[i]); }
  #pragma unroll
  for (int off = 1; off < 64; off <<= 1) m = fmaxf(m, __shfl_xor(m, off, 64));
  __shared__ float sm[4], ss[4];
  int wv = tid >> 6, ln = tid & 63;
  if (ln == 0) sm[wv] = m;
  __syncthreads();
  m = fmaxf(fmaxf(sm[0], sm[1]), fmaxf(sm[2], sm[3]));
  float s = 0.f;
  #pragma unroll
  for (int i = 0; i < 8; ++i) { vals[i] = __expf(vals[i] - m); s += vals[i]; }
  #pragma unroll
  for (int off = 1; off < 64; off <<= 1) s += __shfl_xor(s, off, 64);
  if (ln == 0) ss[wv] = s;
  __syncthreads();
  s = ss[0] + ss[1] + ss[2] + ss[3];
  float inv = 1.f / s;
  #pragma unroll
  for (int i = 0; i < 8; ++i) row[tid + i * 256] = vals[i] * inv;
}

extern "C" void kernel_launch(void* const* d_in, const int* in_sizes, int n_in,
                              void* d_out, int out_size, void* d_ws, size_t ws_size,
                              hipStream_t stream)
{
  const float* enc   = (const float*)d_in[0];
  const float* dh    = (const float*)d_in[1];
  const float* prev  = (const float*)d_in[2];
  const float* Wq    = (const float*)d_in[3];
  const float* Wk    = (const float*)d_in[4];
  const float* convw = (const float*)d_in[5];
  const float* convb = (const float*)d_in[6];
  const float* Wloc  = (const float*)d_in[7];
  const float* v     = (const float*)d_in[8];
  float* out = (float*)d_out;

  // ws layout (needs ~8.6 MB)
  char* w = (char*)d_ws;
  unsigned short* locb  = (unsigned short*)w;               // B*T*32 bf16 = 8,388,608 B
  unsigned short* wkf   = (unsigned short*)(w + 8388608);   // 512*128 bf16 frag-order = 131,072 B
  unsigned short* wlocf = (unsigned short*)(w + 8519680);   // 32*128 bf16 frag-order = 8,192 B
  float*          q2    = (float*)(w + 8527872);            // 64*128 f32 = 32,768 B

  hipLaunchKernelGGL(prep_kernel, dim3(610), dim3(256), 0, stream,
                     prev, convw, dh, Wq, convb, Wloc, Wk, locb, wkf, wlocf, q2);
  hipLaunchKernelGGL(energy_kernel, dim3(2048), dim3(256), 0, stream,
                     enc, locb, wkf, wlocf, q2, v, out);
  hipLaunchKernelGGL(softmax_kernel, dim3(64), dim3(256), 0, stream, out);
}

// Round 2
// 92.123 us; speedup vs baseline: 1.3277x; 1.3277x over previous
//
#include <hip/hip_runtime.h>
#include <hip/hip_bf16.h>

#define B_  64
#define T_  2048
#define E_  512
#define Q_  1024
#define A_  128
#define C_  32
#define KW_ 31

using bf16x8 = __attribute__((ext_vector_type(8))) short;
using f32x4  = __attribute__((ext_vector_type(4))) float;

__device__ __forceinline__ short f2bf(float f) {
  union { float f; unsigned u; } x; x.f = f;
  unsigned r = x.u + 0x7fffu + ((x.u >> 16) & 1u);   // RNE
  return (short)(r >> 16);
}

__device__ __forceinline__ float fast_tanh(float x) {
  // |x| large -> exp overflows to inf -> rcp -> 0 -> ±1: still correct, no clamp
  float e2 = __expf(2.f * x);
  return 1.f - 2.f * __builtin_amdgcn_rcpf(e2 + 1.f);
}

// ---------------- prep: q2 = dh@Wq + conv_b@Wloc; Wk,Wloc -> MFMA B-frag order (bf16)
__global__ __launch_bounds__(256) void prep_kernel(
    const float* __restrict__ dh, const float* __restrict__ Wq,
    const float* __restrict__ conv_b, const float* __restrict__ Wloc,
    const float* __restrict__ Wk,
    unsigned short* __restrict__ wkf, unsigned short* __restrict__ wlocf,
    float* __restrict__ q2)
{
  int blk = blockIdx.x;
  int tid = threadIdx.x;
  if (blk < 64) {
    // q2[b,a] = sum_k dh[b,k]*Wq[k,a] + sum_c conv_b[c]*Wloc[c,a]; 2-way K split
    __shared__ float part[128];
    int a = tid & 127, kh = tid >> 7;
    const float* dhr = dh + blk * Q_ + kh * 512;
    const float* wq  = Wq + (size_t)kh * 512 * A_ + a;
    float s = 0.f;
    #pragma unroll 8
    for (int k = 0; k < 512; ++k) s += dhr[k] * wq[(size_t)k * A_];
    if (kh) part[a] = s;
    __syncthreads();
    if (!kh) {
      s += part[a];
      for (int c = 0; c < C_; ++c) s += conv_b[c] * Wloc[c * A_ + a];
      q2[blk * A_ + a] = s;
    }
  } else if (blk < 96) {
    // Wk -> B-frag order: group g=(ks,nt); elem j: k=ks*32+(lane>>4)*8+j, n=nt*16+(lane&15)
    int wave = tid >> 6, lane = tid & 63;
    int g = (blk - 64) * 4 + wave;           // 0..127
    int ks = g >> 3, nt = g & 7;
    int lg = lane >> 4, lr = lane & 15;
    bf16x8 o;
    #pragma unroll
    for (int j = 0; j < 8; ++j)
      o[j] = f2bf(Wk[(ks * 32 + lg * 8 + j) * A_ + nt * 16 + lr]);
    *(bf16x8*)(wkf + ((size_t)g * 64 + lane) * 8) = o;
  } else {
    // Wloc -> B-frag order (single K-step of 32 = conv channels)
    int wave = tid >> 6, lane = tid & 63;
    int g = (blk - 96) * 4 + wave;           // 0..7
    int lg = lane >> 4, lr = lane & 15;
    bf16x8 o;
    #pragma unroll
    for (int j = 0; j < 8; ++j)
      o[j] = f2bf(Wloc[(lg * 8 + j) * A_ + g * 16 + lr]);
    *(bf16x8*)(wlocf + ((size_t)g * 64 + lane) * 8) = o;
  }
}

// ---------------- energy[b,t] = v . tanh(enc@Wk + q2[b] + conv(prev)@Wloc)
// 1024 blocks x 4 waves; wave = 32 rows (M-rep=2); conv computed per-block in LDS
__global__ __launch_bounds__(256) void energy_kernel(
    const float* __restrict__ enc, const float* __restrict__ prev,
    const float* __restrict__ conv_w,
    const unsigned short* __restrict__ wkf, const unsigned short* __restrict__ wlocf,
    const float* __restrict__ q2, const float* __restrict__ vvec,
    float* __restrict__ energy)
{
  __shared__ float sprev[160];                 // 158 used (128 + 30 halo)
  __shared__ float scw[KW_][C_];
  __shared__ unsigned short slocb[128][C_];    // conv out, bf16, 8 KB
  int tid = threadIdx.x;
  int m0 = blockIdx.x * 128;                   // flattened b*T + t base
  int b  = m0 >> 11, t0 = m0 & (T_ - 1);

  for (int i = tid; i < 158; i += 256) {
    int t = t0 - 15 + i;
    sprev[i] = (t >= 0 && t < T_) ? prev[b * T_ + t] : 0.f;
  }
  for (int i = tid; i < KW_ * C_; i += 256) {
    int j = i >> 5, c = i & 31;
    scw[j][c] = conv_w[c * KW_ + j];
  }
  __syncthreads();
  {
    // thread: t_local = tid>>1, channels (tid&1)*16..+15
    int tl = tid >> 1, ch0 = (tid & 1) * 16;
    float acc[16];
    #pragma unroll
    for (int c = 0; c < 16; ++c) acc[c] = 0.f;
    for (int j = 0; j < KW_; ++j) {
      float p = sprev[tl + j];
      #pragma unroll
      for (int c = 0; c < 16; ++c) acc[c] += p * scw[j][ch0 + c];
    }
    unsigned int* dstp = (unsigned int*)&slocb[tl][ch0];
    #pragma unroll
    for (int c = 0; c < 16; c += 2)
      dstp[c >> 1] = ((unsigned int)(unsigned short)f2bf(acc[c + 1]) << 16)
                   | (unsigned short)f2bf(acc[c]);
  }
  __syncthreads();

  int wave = tid >> 6, lane = tid & 63;
  int lg = lane >> 4, lr = lane & 15;
  int wm = m0 + wave * 32;                     // this wave's 32 rows

  const float* encRow0 = enc + (size_t)(wm + lr) * E_ + lg * 8;
  const float* encRow1 = encRow0 + 16 * E_;

  f32x4 acc0[8], acc1[8];
  #pragma unroll
  for (int i = 0; i < 8; ++i) { acc0[i] = (f32x4){0,0,0,0}; acc1[i] = (f32x4){0,0,0,0}; }

  const unsigned short* wkl = wkf + (size_t)lane * 8;
  for (int ks = 0; ks < 16; ++ks) {
    float4 a0 = *(const float4*)(encRow0 + ks * 32);
    float4 a1 = *(const float4*)(encRow0 + ks * 32 + 4);
    float4 a2 = *(const float4*)(encRow1 + ks * 32);
    float4 a3 = *(const float4*)(encRow1 + ks * 32 + 4);
    bf16x8 af0, af1;
    af0[0]=f2bf(a0.x); af0[1]=f2bf(a0.y); af0[2]=f2bf(a0.z); af0[3]=f2bf(a0.w);
    af0[4]=f2bf(a1.x); af0[5]=f2bf(a1.y); af0[6]=f2bf(a1.z); af0[7]=f2bf(a1.w);
    af1[0]=f2bf(a2.x); af1[1]=f2bf(a2.y); af1[2]=f2bf(a2.z); af1[3]=f2bf(a2.w);
    af1[4]=f2bf(a3.x); af1[5]=f2bf(a3.y); af1[6]=f2bf(a3.z); af1[7]=f2bf(a3.w);
    #pragma unroll
    for (int nt = 0; nt < 8; ++nt) {
      bf16x8 bf = *(const bf16x8*)(wkl + (size_t)(ks * 8 + nt) * 64 * 8);
      acc0[nt] = __builtin_amdgcn_mfma_f32_16x16x32_bf16(af0, bf, acc0[nt], 0, 0, 0);
      acc1[nt] = __builtin_amdgcn_mfma_f32_16x16x32_bf16(af1, bf, acc1[nt], 0, 0, 0);
    }
  }
  { // location term: one extra K=32 MFMA step (K = conv channels), A from LDS
    int lrow = wave * 32 + lr;
    bf16x8 af0 = *(const bf16x8*)&slocb[lrow][lg * 8];
    bf16x8 af1 = *(const bf16x8*)&slocb[lrow + 16][lg * 8];
    #pragma unroll
    for (int nt = 0; nt < 8; ++nt) {
      bf16x8 bf = *(const bf16x8*)(wlocf + ((size_t)nt * 64 + lane) * 8);
      acc0[nt] = __builtin_amdgcn_mfma_f32_16x16x32_bf16(af0, bf, acc0[nt], 0, 0, 0);
      acc1[nt] = __builtin_amdgcn_mfma_f32_16x16x32_bf16(af1, bf, acc1[nt], 0, 0, 0);
    }
  }
  // D layout: col = nt*16 + lr, rows = base + lg*4 + r ; epilogue for both frags
  const float* q2r = q2 + b * A_;
  #pragma unroll
  for (int f = 0; f < 2; ++f) {
    f32x4* acc = f ? acc1 : acc0;
    float p0 = 0, p1 = 0, p2 = 0, p3 = 0;
    #pragma unroll
    for (int nt = 0; nt < 8; ++nt) {
      int n = nt * 16 + lr;
      float qv = q2r[n];
      float vv = vvec[n];
      p0 += fast_tanh(acc[nt][0] + qv) * vv;
      p1 += fast_tanh(acc[nt][1] + qv) * vv;
      p2 += fast_tanh(acc[nt][2] + qv) * vv;
      p3 += fast_tanh(acc[nt][3] + qv) * vv;
    }
    #pragma unroll
    for (int off = 1; off < 16; off <<= 1) {
      p0 += __shfl_xor(p0, off, 64);
      p1 += __shfl_xor(p1, off, 64);
      p2 += __shfl_xor(p2, off, 64);
      p3 += __shfl_xor(p3, off, 64);
    }
    if (lr == 0)
      *(float4*)(energy + wm + f * 16 + lg * 4) = make_float4(p0, p1, p2, p3);
  }
}

// ---------------- softmax over T per row b, in-place on d_out
__global__ __launch_bounds__(256) void softmax_kernel(float* __restrict__ out)
{
  int bb = blockIdx.x;
  int tid = threadIdx.x;
  float* row = out + (size_t)bb * T_;
  float vals[8];
  float m = -1e30f;
  #pragma unroll
  for (int i = 0; i < 8; ++i) { vals[i] = row[tid + i * 256]; m = fmaxf(m, vals[i]); }
  #pragma unroll
  for (int off = 1; off < 64; off <<= 1) m = fmaxf(m, __shfl_xor(m, off, 64));
  __shared__ float sm[4], ss[4];
  int wv = tid >> 6, ln = tid & 63;
  if (ln == 0) sm[wv] = m;
  __syncthreads();
  m = fmaxf(fmaxf(sm[0], sm[1]), fmaxf(sm[2], sm[3]));
  float s = 0.f;
  #pragma unroll
  for (int i = 0; i < 8; ++i) { vals[i] = __expf(vals[i] - m); s += vals[i]; }
  #pragma unroll
  for (int off = 1; off < 64; off <<= 1) s += __shfl_xor(s, off, 64);
  if (ln == 0) ss[wv] = s;
  __syncthreads();
  s = ss[0] + ss[1] + ss[2] + ss[3];
  float inv = 1.f / s;
  #pragma unroll
  for (int i = 0; i < 8; ++i) row[tid + i * 256] = vals[i] * inv;
}

extern "C" void kernel_launch(void* const* d_in, const int* in_sizes, int n_in,
                              void* d_out, int out_size, void* d_ws, size_t ws_size,
                              hipStream_t stream)
{
  const float* enc   = (const float*)d_in[0];
  const float* dh    = (const float*)d_in[1];
  const float* prev  = (const float*)d_in[2];
  const float* Wq    = (const float*)d_in[3];
  const float* Wk    = (const float*)d_in[4];
  const float* convw = (const float*)d_in[5];
  const float* convb = (const float*)d_in[6];
  const float* Wloc  = (const float*)d_in[7];
  const float* v     = (const float*)d_in[8];
  float* out = (float*)d_out;

  char* w = (char*)d_ws;
  unsigned short* wkf   = (unsigned short*)w;               // 512*128 bf16 frag-order = 131,072 B
  unsigned short* wlocf = (unsigned short*)(w + 131072);    // 32*128 bf16 frag-order = 8,192 B
  float*          q2    = (float*)(w + 139264);             // 64*128 f32 = 32,768 B

  hipLaunchKernelGGL(prep_kernel, dim3(98), dim3(256), 0, stream,
                     dh, Wq, convb, Wloc, Wk, wkf, wlocf, q2);
  hipLaunchKernelGGL(energy_kernel, dim3(1024), dim3(256), 0, stream,
                     enc, prev, convw, wkf, wlocf, q2, v, out);
  hipLaunchKernelGGL(softmax_kernel, dim3(64), dim3(256), 0, stream, out);
}

// Round 3
// 78.853 us; speedup vs baseline: 1.5511x; 1.1683x over previous
//
#include <hip/hip_runtime.h>
#include <hip/hip_bf16.h>

#define B_  64
#define T_  2048
#define E_  512
#define Q_  1024
#define A_  128
#define C_  32
#define KW_ 31

using bf16x8 = __attribute__((ext_vector_type(8))) short;
using f32x4  = __attribute__((ext_vector_type(4))) float;

__device__ __forceinline__ short f2bf(float f) {
  union { float f; unsigned u; } x; x.f = f;
  unsigned r = x.u + 0x7fffu + ((x.u >> 16) & 1u);   // RNE
  return (short)(r >> 16);
}

__device__ __forceinline__ bf16x8 pack8(float4 a, float4 b) {
  union { bf16x8 v; __hip_bfloat162 h[4]; } u;
  u.h[0] = __float22bfloat162_rn(make_float2(a.x, a.y));
  u.h[1] = __float22bfloat162_rn(make_float2(a.z, a.w));
  u.h[2] = __float22bfloat162_rn(make_float2(b.x, b.y));
  u.h[3] = __float22bfloat162_rn(make_float2(b.z, b.w));
  return u.v;
}

__device__ __forceinline__ float fast_tanh(float x) {
  // |x| large -> exp -> inf -> rcp -> 0 -> ±1: still correct, no clamp needed
  float e2 = __expf(2.f * x);
  return 1.f - 2.f * __builtin_amdgcn_rcpf(e2 + 1.f);
}

// ---------------- prep: q2 partials (b x 8 K-slices); Wk,Wloc -> MFMA B-frag order (bf16)
__global__ __launch_bounds__(256) void prep_kernel(
    const float* __restrict__ dh, const float* __restrict__ Wq,
    const float* __restrict__ conv_b, const float* __restrict__ Wloc,
    const float* __restrict__ Wk,
    unsigned short* __restrict__ wkf, unsigned short* __restrict__ wlocf,
    float* __restrict__ q2p)
{
  int blk = blockIdx.x;
  int tid = threadIdx.x;
  if (blk < 512) {
    // q2p[kq][b][a] = sum over k in [kq*128, kq*128+128) of dh[b,k]*Wq[k,a]
    __shared__ float part[128];
    int b = blk >> 3, kq = blk & 7;
    int a = tid & 127, kh = tid >> 7;
    const float* dhr = dh + b * Q_ + kq * 128 + kh * 64;
    const float* wq  = Wq + (size_t)(kq * 128 + kh * 64) * A_ + a;
    float s = 0.f;
    #pragma unroll 8
    for (int k = 0; k < 64; ++k) s += dhr[k] * wq[(size_t)k * A_];
    if (kh) part[a] = s;
    __syncthreads();
    if (!kh) {
      s += part[a];
      if (kq == 0) {                      // fold conv bias term once
        float t = 0.f;
        #pragma unroll 8
        for (int c = 0; c < C_; ++c) t += conv_b[c] * Wloc[c * A_ + a];
        s += t;
      }
      q2p[(kq * B_ + b) * A_ + a] = s;
    }
  } else if (blk < 544) {
    // Wk -> B-frag order: group g=(ks,nt); elem j: k=ks*32+(lane>>4)*8+j, n=nt*16+(lane&15)
    int wave = tid >> 6, lane = tid & 63;
    int g = (blk - 512) * 4 + wave;          // 0..127
    int ks = g >> 3, nt = g & 7;
    int lg = lane >> 4, lr = lane & 15;
    bf16x8 o;
    #pragma unroll
    for (int j = 0; j < 8; ++j)
      o[j] = f2bf(Wk[(ks * 32 + lg * 8 + j) * A_ + nt * 16 + lr]);
    *(bf16x8*)(wkf + ((size_t)g * 64 + lane) * 8) = o;
  } else {
    // Wloc -> B-frag order (single K-step of 32 = conv channels)
    int wave = tid >> 6, lane = tid & 63;
    int g = (blk - 544) * 4 + wave;          // 0..7
    int lg = lane >> 4, lr = lane & 15;
    bf16x8 o;
    #pragma unroll
    for (int j = 0; j < 8; ++j)
      o[j] = f2bf(Wloc[(lg * 8 + j) * A_ + g * 16 + lr]);
    *(bf16x8*)(wlocf + ((size_t)g * 64 + lane) * 8) = o;
  }
}

// ---------------- energy[b,t] = v . tanh(enc@Wk + q2[b] + conv(prev)@Wloc)
// 1024 blocks x 4 waves; wave = 32 rows (M-rep=2); conv computed per-block in LDS
__global__ __launch_bounds__(256) void energy_kernel(
    const float* __restrict__ enc, const float* __restrict__ prev,
    const float* __restrict__ conv_w,
    const unsigned short* __restrict__ wkf, const unsigned short* __restrict__ wlocf,
    const float* __restrict__ q2p, const float* __restrict__ vvec,
    float* __restrict__ energy)
{
  __shared__ float sprev[160];                 // 158 used (128 + 30 halo)
  __shared__ float scw[KW_][C_];
  __shared__ unsigned short slocb[128][C_];    // conv out, bf16, 8 KB
  int tid = threadIdx.x;
  int m0 = blockIdx.x * 128;                   // flattened b*T + t base
  int b  = m0 >> 11, t0 = m0 & (T_ - 1);

  for (int i = tid; i < 158; i += 256) {
    int t = t0 - 15 + i;
    sprev[i] = (t >= 0 && t < T_) ? prev[b * T_ + t] : 0.f;
  }
  for (int i = tid; i < KW_ * C_; i += 256) {
    int j = i >> 5, c = i & 31;
    scw[j][c] = conv_w[c * KW_ + j];
  }
  __syncthreads();
  {
    // conv: thread t_local = tid>>1, channels (tid&1)*16..+15
    int tl = tid >> 1, ch0 = (tid & 1) * 16;
    float acc[16];
    #pragma unroll
    for (int c = 0; c < 16; ++c) acc[c] = 0.f;
    for (int j = 0; j < KW_; ++j) {
      float p = sprev[tl + j];
      #pragma unroll
      for (int c = 0; c < 16; ++c) acc[c] += p * scw[j][ch0 + c];
    }
    unsigned int* dstp = (unsigned int*)&slocb[tl][ch0];
    #pragma unroll
    for (int c = 0; c < 16; c += 2)
      dstp[c >> 1] = ((unsigned int)(unsigned short)f2bf(acc[c + 1]) << 16)
                   | (unsigned short)f2bf(acc[c]);
  }
  __syncthreads();

  int wave = tid >> 6, lane = tid & 63;
  int lg = lane >> 4, lr = lane & 15;
  int wm = m0 + wave * 32;                     // this wave's 32 rows

  const float* encRow0 = enc + (size_t)(wm + lr) * E_ + lg * 8;
  const float* encRow1 = encRow0 + 16 * E_;

  f32x4 acc0[8], acc1[8];
  #pragma unroll
  for (int i = 0; i < 8; ++i) { acc0[i] = (f32x4){0,0,0,0}; acc1[i] = (f32x4){0,0,0,0}; }

  const unsigned short* wkl = wkf + (size_t)lane * 8;
  #pragma unroll 2
  for (int ks = 0; ks < 16; ++ks) {
    float4 a0 = *(const float4*)(encRow0 + ks * 32);
    float4 a1 = *(const float4*)(encRow0 + ks * 32 + 4);
    float4 a2 = *(const float4*)(encRow1 + ks * 32);
    float4 a3 = *(const float4*)(encRow1 + ks * 32 + 4);
    bf16x8 af0 = pack8(a0, a1);
    bf16x8 af1 = pack8(a2, a3);
    #pragma unroll
    for (int nt = 0; nt < 8; ++nt) {
      bf16x8 bf = *(const bf16x8*)(wkl + (size_t)(ks * 8 + nt) * 64 * 8);
      acc0[nt] = __builtin_amdgcn_mfma_f32_16x16x32_bf16(af0, bf, acc0[nt], 0, 0, 0);
      acc1[nt] = __builtin_amdgcn_mfma_f32_16x16x32_bf16(af1, bf, acc1[nt], 0, 0, 0);
    }
  }
  { // location term: one extra K=32 MFMA step (K = conv channels), A from LDS
    int lrow = wave * 32 + lr;
    bf16x8 af0 = *(const bf16x8*)&slocb[lrow][lg * 8];
    bf16x8 af1 = *(const bf16x8*)&slocb[lrow + 16][lg * 8];
    #pragma unroll
    for (int nt = 0; nt < 8; ++nt) {
      bf16x8 bf = *(const bf16x8*)(wlocf + ((size_t)nt * 64 + lane) * 8);
      acc0[nt] = __builtin_amdgcn_mfma_f32_16x16x32_bf16(af0, bf, acc0[nt], 0, 0, 0);
      acc1[nt] = __builtin_amdgcn_mfma_f32_16x16x32_bf16(af1, bf, acc1[nt], 0, 0, 0);
    }
  }
  // epilogue: q2 = sum of 8 partials (L2-hot), then v . tanh(acc + q2)
  float qv[8], vv[8];
  #pragma unroll
  for (int nt = 0; nt < 8; ++nt) {
    int n = nt * 16 + lr;
    float s = 0.f;
    #pragma unroll
    for (int p = 0; p < 8; ++p) s += q2p[(p * B_ + b) * A_ + n];
    qv[nt] = s;
    vv[nt] = vvec[n];
  }
  #pragma unroll
  for (int f = 0; f < 2; ++f) {
    f32x4* acc = f ? acc1 : acc0;
    float p0 = 0, p1 = 0, p2 = 0, p3 = 0;
    #pragma unroll
    for (int nt = 0; nt < 8; ++nt) {
      p0 += fast_tanh(acc[nt][0] + qv[nt]) * vv[nt];
      p1 += fast_tanh(acc[nt][1] + qv[nt]) * vv[nt];
      p2 += fast_tanh(acc[nt][2] + qv[nt]) * vv[nt];
      p3 += fast_tanh(acc[nt][3] + qv[nt]) * vv[nt];
    }
    #pragma unroll
    for (int off = 1; off < 16; off <<= 1) {
      p0 += __shfl_xor(p0, off, 64);
      p1 += __shfl_xor(p1, off, 64);
      p2 += __shfl_xor(p2, off, 64);
      p3 += __shfl_xor(p3, off, 64);
    }
    if (lr == 0)
      *(float4*)(energy + wm + f * 16 + lg * 4) = make_float4(p0, p1, p2, p3);
  }
}

// ---------------- softmax over T per row b, in-place on d_out
__global__ __launch_bounds__(256) void softmax_kernel(float* __restrict__ out)
{
  int bb = blockIdx.x;
  int tid = threadIdx.x;
  float* row = out + (size_t)bb * T_;
  float vals[8];
  float m = -1e30f;
  #pragma unroll
  for (int i = 0; i < 8; ++i) { vals[i] = row[tid + i * 256]; m = fmaxf(m, vals[i]); }
  #pragma unroll
  for (int off = 1; off < 64; off <<= 1) m = fmaxf(m, __shfl_xor(m, off, 64));
  __shared__ float sm[4], ss[4];
  int wv = tid >> 6, ln = tid & 63;
  if (ln == 0) sm[wv] = m;
  __syncthreads();
  m = fmaxf(fmaxf(sm[0], sm[1]), fmaxf(sm[2], sm[3]));
  float s = 0.f;
  #pragma unroll
  for (int i = 0; i < 8; ++i) { vals[i] = __expf(vals[i] - m); s += vals[i]; }
  #pragma unroll
  for (int off = 1; off < 64; off <<= 1) s += __shfl_xor(s, off, 64);
  if (ln == 0) ss[wv] = s;
  __syncthreads();
  s = ss[0] + ss[1] + ss[2] + ss[3];
  float inv = 1.f / s;
  #pragma unroll
  for (int i = 0; i < 8; ++i) row[tid + i * 256] = vals[i] * inv;
}

extern "C" void kernel_launch(void* const* d_in, const int* in_sizes, int n_in,
                              void* d_out, int out_size, void* d_ws, size_t ws_size,
                              hipStream_t stream)
{
  const float* enc   = (const float*)d_in[0];
  const float* dh    = (const float*)d_in[1];
  const float* prev  = (const float*)d_in[2];
  const float* Wq    = (const float*)d_in[3];
  const float* Wk    = (const float*)d_in[4];
  const float* convw = (const float*)d_in[5];
  const float* convb = (const float*)d_in[6];
  const float* Wloc  = (const float*)d_in[7];
  const float* v     = (const float*)d_in[8];
  float* out = (float*)d_out;

  char* w = (char*)d_ws;
  unsigned short* wkf   = (unsigned short*)w;               // 512*128 bf16 frag-order = 131,072 B
  unsigned short* wlocf = (unsigned short*)(w + 131072);    // 32*128 bf16 frag-order = 8,192 B
  float*          q2p   = (float*)(w + 139264);             // 8*64*128 f32 partials = 262,144 B

  hipLaunchKernelGGL(prep_kernel, dim3(546), dim3(256), 0, stream,
                     dh, Wq, convb, Wloc, Wk, wkf, wlocf, q2p);
  hipLaunchKernelGGL(energy_kernel, dim3(1024), dim3(256), 0, stream,
                     enc, prev, convw, wkf, wlocf, q2p, v, out);
  hipLaunchKernelGGL(softmax_kernel, dim3(64), dim3(256), 0, stream, out);
}

// Round 4
// 72.727 us; speedup vs baseline: 1.6818x; 1.0842x over previous
//
#include <hip/hip_runtime.h>
#include <hip/hip_bf16.h>

#define B_  64
#define T_  2048
#define E_  512
#define Q_  1024
#define A_  128
#define C_  32
#define KW_ 31

using bf16x8 = __attribute__((ext_vector_type(8))) short;
using f32x4  = __attribute__((ext_vector_type(4))) float;

__device__ __forceinline__ short f2bf(float f) {
  union { float f; unsigned u; } x; x.f = f;
  unsigned r = x.u + 0x7fffu + ((x.u >> 16) & 1u);   // RNE
  return (short)(r >> 16);
}

__device__ __forceinline__ bf16x8 pack8(float4 a, float4 b) {
  union { bf16x8 v; __hip_bfloat162 h[4]; } u;
  u.h[0] = __float22bfloat162_rn(make_float2(a.x, a.y));
  u.h[1] = __float22bfloat162_rn(make_float2(a.z, a.w));
  u.h[2] = __float22bfloat162_rn(make_float2(b.x, b.y));
  u.h[3] = __float22bfloat162_rn(make_float2(b.z, b.w));
  return u.v;
}

__device__ __forceinline__ float fast_tanh(float x) {
  float e2 = __expf(2.f * x);
  return 1.f - 2.f * __builtin_amdgcn_rcpf(e2 + 1.f);
}

__device__ __forceinline__ void gload16(const void* g, void* l) {
  __builtin_amdgcn_global_load_lds(
      (const __attribute__((address_space(1))) unsigned int*)g,
      (__attribute__((address_space(3))) unsigned int*)l, 16, 0, 0);
}

// ---------------- prep: q2 partials (b x 8 K-slices); Wk,Wloc -> MFMA B-frag order (bf16)
__global__ __launch_bounds__(256) void prep_kernel(
    const float* __restrict__ dh, const float* __restrict__ Wq,
    const float* __restrict__ conv_b, const float* __restrict__ Wloc,
    const float* __restrict__ Wk,
    unsigned short* __restrict__ wkf, unsigned short* __restrict__ wlocf,
    float* __restrict__ q2p)
{
  int blk = blockIdx.x;
  int tid = threadIdx.x;
  if (blk < 512) {
    __shared__ float part[128];
    int b = blk >> 3, kq = blk & 7;
    int a = tid & 127, kh = tid >> 7;
    const float* dhr = dh + b * Q_ + kq * 128 + kh * 64;
    const float* wq  = Wq + (size_t)(kq * 128 + kh * 64) * A_ + a;
    float s = 0.f;
    #pragma unroll 8
    for (int k = 0; k < 64; ++k) s += dhr[k] * wq[(size_t)k * A_];
    if (kh) part[a] = s;
    __syncthreads();
    if (!kh) {
      s += part[a];
      if (kq == 0) {
        float t = 0.f;
        #pragma unroll 8
        for (int c = 0; c < C_; ++c) t += conv_b[c] * Wloc[c * A_ + a];
        s += t;
      }
      q2p[(kq * B_ + b) * A_ + a] = s;
    }
  } else if (blk < 544) {
    int wave = tid >> 6, lane = tid & 63;
    int g = (blk - 512) * 4 + wave;          // 0..127
    int ks = g >> 3, nt = g & 7;
    int lg = lane >> 4, lr = lane & 15;
    bf16x8 o;
    #pragma unroll
    for (int j = 0; j < 8; ++j)
      o[j] = f2bf(Wk[(ks * 32 + lg * 8 + j) * A_ + nt * 16 + lr]);
    *(bf16x8*)(wkf + ((size_t)g * 64 + lane) * 8) = o;
  } else {
    int wave = tid >> 6, lane = tid & 63;
    int g = (blk - 544) * 4 + wave;          // 0..7
    int lg = lane >> 4, lr = lane & 15;
    bf16x8 o;
    #pragma unroll
    for (int j = 0; j < 8; ++j)
      o[j] = f2bf(Wloc[(lg * 8 + j) * A_ + g * 16 + lr]);
    *(bf16x8*)(wlocf + ((size_t)g * 64 + lane) * 8) = o;
  }
}

// ---------------- energy: out = exp(v . tanh(enc@Wk + q2[b] + conv(prev)@Wloc)), psum partials
// B-fragments staged per-block through double-buffered LDS (global_load_lds),
// counted vmcnt(4) keeps A-prefetch in flight across raw s_barrier (T3/T4).
__global__ __launch_bounds__(256, 4) void energy_kernel(
    const float* __restrict__ enc, const float* __restrict__ prev,
    const float* __restrict__ conv_w,
    const unsigned short* __restrict__ wkfall,   // wkf slices 0..15, wlocf = slice 16
    const float* __restrict__ q2p, const float* __restrict__ vvec,
    float* __restrict__ outexp, float* __restrict__ psum)
{
  __shared__ unsigned short sB0[4096];   // 8 KB double buffer for B frags
  __shared__ unsigned short sB1[4096];
  __shared__ float sprev[160];
  __shared__ float scw[KW_][C_];
  __shared__ unsigned short slocb[128][C_];
  __shared__ float swsum[4];

  int tid = threadIdx.x;
  int m0 = blockIdx.x * 128;
  int b  = m0 >> 11, t0 = m0 & (T_ - 1);

  for (int i = tid; i < 158; i += 256) {
    int t = t0 - 15 + i;
    sprev[i] = (t >= 0 && t < T_) ? prev[b * T_ + t] : 0.f;
  }
  for (int i = tid; i < KW_ * C_; i += 256) {
    int j = i >> 5, c = i & 31;
    scw[j][c] = conv_w[c * KW_ + j];
  }
  __syncthreads();
  {
    int tl = tid >> 1, ch0 = (tid & 1) * 16;
    float acc[16];
    #pragma unroll
    for (int c = 0; c < 16; ++c) acc[c] = 0.f;
    for (int j = 0; j < KW_; ++j) {
      float p = sprev[tl + j];
      #pragma unroll
      for (int c = 0; c < 16; ++c) acc[c] += p * scw[j][ch0 + c];
    }
    unsigned int* dstp = (unsigned int*)&slocb[tl][ch0];
    #pragma unroll
    for (int c = 0; c < 16; c += 2)
      dstp[c >> 1] = ((unsigned int)(unsigned short)f2bf(acc[c + 1]) << 16)
                   | (unsigned short)f2bf(acc[c]);
  }
  __syncthreads();   // slocb ready; full drain (pre-loop, fine)

  int wave = tid >> 6, lane = tid & 63;
  int lg = lane >> 4, lr = lane & 15;
  int wm = m0 + wave * 32;

  const float* encRow0 = enc + (size_t)(wm + lr) * E_ + lg * 8;
  const float* encRow1 = encRow0 + 16 * E_;

  // stage one 8 KB B-slice: per wave 2x 1 KB (lane-linear dest, per-lane src)
  #define STAGE(slice, buf) do {                                              \
    const unsigned short* s_ = wkfall + (size_t)(slice) * 4096 + wave * 512 + lane * 8; \
    gload16(s_,        &buf[wave * 512]);                                     \
    gload16(s_ + 2048, &buf[(4 + wave) * 512]);                               \
  } while (0)

  f32x4 acc0[8], acc1[8];
  #pragma unroll
  for (int i = 0; i < 8; ++i) { acc0[i] = (f32x4){0,0,0,0}; acc1[i] = (f32x4){0,0,0,0}; }

  float4 aA0, aA1, aA2, aA3, aB0, aB1, aB2, aB3;

  // prologue: stage slice 0, prefetch A(0); stage ops are oldest -> vmcnt(4) drains them
  STAGE(0, sB0);
  __builtin_amdgcn_sched_barrier(0);
  aA0 = *(const float4*)(encRow0);     aA1 = *(const float4*)(encRow0 + 4);
  aA2 = *(const float4*)(encRow1);     aA3 = *(const float4*)(encRow1 + 4);
  asm volatile("s_waitcnt vmcnt(4)" ::: "memory");
  __builtin_amdgcn_sched_barrier(0);
  __builtin_amdgcn_s_barrier();

  #pragma unroll 1
  for (int i = 0; i < 8; ++i) {
    // ---- even step ks=2i: read sB0, stage slice 2i+1 -> sB1, prefetch A(2i+1)
    STAGE(2 * i + 1, sB1);
    __builtin_amdgcn_sched_barrier(0);
    {
      const float* r0 = encRow0 + (2 * i + 1) * 32;
      const float* r1 = encRow1 + (2 * i + 1) * 32;
      aB0 = *(const float4*)(r0); aB1 = *(const float4*)(r0 + 4);
      aB2 = *(const float4*)(r1); aB3 = *(const float4*)(r1 + 4);
    }
    {
      bf16x8 af0 = pack8(aA0, aA1), af1 = pack8(aA2, aA3);
      #pragma unroll
      for (int nt = 0; nt < 8; ++nt) {
        bf16x8 bfr = *(const bf16x8*)&sB0[nt * 512 + lane * 8];
        acc0[nt] = __builtin_amdgcn_mfma_f32_16x16x32_bf16(af0, bfr, acc0[nt], 0, 0, 0);
        acc1[nt] = __builtin_amdgcn_mfma_f32_16x16x32_bf16(af1, bfr, acc1[nt], 0, 0, 0);
      }
    }
    asm volatile("s_waitcnt vmcnt(4) lgkmcnt(0)" ::: "memory");
    __builtin_amdgcn_sched_barrier(0);
    __builtin_amdgcn_s_barrier();

    // ---- odd step ks=2i+1: read sB1, stage slice 2i+2 -> sB0 (slice 16 = wlocf)
    STAGE(2 * i + 2, sB0);
    __builtin_amdgcn_sched_barrier(0);
    if (i < 7) {
      const float* r0 = encRow0 + (2 * i + 2) * 32;
      const float* r1 = encRow1 + (2 * i + 2) * 32;
      aA0 = *(const float4*)(r0); aA1 = *(const float4*)(r0 + 4);
      aA2 = *(const float4*)(r1); aA3 = *(const float4*)(r1 + 4);
    }
    {
      bf16x8 af0 = pack8(aB0, aB1), af1 = pack8(aB2, aB3);
      #pragma unroll
      for (int nt = 0; nt < 8; ++nt) {
        bf16x8 bfr = *(const bf16x8*)&sB1[nt * 512 + lane * 8];
        acc0[nt] = __builtin_amdgcn_mfma_f32_16x16x32_bf16(af0, bfr, acc0[nt], 0, 0, 0);
        acc1[nt] = __builtin_amdgcn_mfma_f32_16x16x32_bf16(af1, bfr, acc1[nt], 0, 0, 0);
      }
    }
    if (i < 7) { asm volatile("s_waitcnt vmcnt(4) lgkmcnt(0)" ::: "memory"); }
    else       { asm volatile("s_waitcnt vmcnt(0) lgkmcnt(0)" ::: "memory"); }
    __builtin_amdgcn_sched_barrier(0);
    __builtin_amdgcn_s_barrier();
  }

  { // location term: slice 16 (wlocf) now in sB0; A from slocb
    int lrow = wave * 32 + lr;
    bf16x8 af0 = *(const bf16x8*)&slocb[lrow][lg * 8];
    bf16x8 af1 = *(const bf16x8*)&slocb[lrow + 16][lg * 8];
    #pragma unroll
    for (int nt = 0; nt < 8; ++nt) {
      bf16x8 bfr = *(const bf16x8*)&sB0[nt * 512 + lane * 8];
      acc0[nt] = __builtin_amdgcn_mfma_f32_16x16x32_bf16(af0, bfr, acc0[nt], 0, 0, 0);
      acc1[nt] = __builtin_amdgcn_mfma_f32_16x16x32_bf16(af1, bfr, acc1[nt], 0, 0, 0);
    }
  }

  // epilogue: qv = sum of 8 q2 partials; p = v.tanh(acc+qv); out = exp(p); psum partial
  float qv[8], vv[8];
  #pragma unroll
  for (int nt = 0; nt < 8; ++nt) {
    int n = nt * 16 + lr;
    float s = 0.f;
    #pragma unroll
    for (int p = 0; p < 8; ++p) s += q2p[(p * B_ + b) * A_ + n];
    qv[nt] = s;
    vv[nt] = vvec[n];
  }
  float ssum = 0.f;
  #pragma unroll
  for (int f = 0; f < 2; ++f) {
    f32x4* acc = f ? acc1 : acc0;
    float p0 = 0, p1 = 0, p2 = 0, p3 = 0;
    #pragma unroll
    for (int nt = 0; nt < 8; ++nt) {
      p0 += fast_tanh(acc[nt][0] + qv[nt]) * vv[nt];
      p1 += fast_tanh(acc[nt][1] + qv[nt]) * vv[nt];
      p2 += fast_tanh(acc[nt][2] + qv[nt]) * vv[nt];
      p3 += fast_tanh(acc[nt][3] + qv[nt]) * vv[nt];
    }
    #pragma unroll
    for (int off = 1; off < 16; off <<= 1) {
      p0 += __shfl_xor(p0, off, 64);
      p1 += __shfl_xor(p1, off, 64);
      p2 += __shfl_xor(p2, off, 64);
      p3 += __shfl_xor(p3, off, 64);
    }
    float e0 = __expf(p0), e1 = __expf(p1), e2 = __expf(p2), e3 = __expf(p3);
    ssum += (e0 + e1) + (e2 + e3);
    if (lr == 0)
      *(float4*)(outexp + wm + f * 16 + lg * 4) = make_float4(e0, e1, e2, e3);
  }
  ssum += __shfl_xor(ssum, 16, 64);
  ssum += __shfl_xor(ssum, 32, 64);
  if (lane == 0) swsum[wave] = ssum;
  __syncthreads();
  if (tid == 0)
    psum[b * 16 + (blockIdx.x & 15)] = (swsum[0] + swsum[1]) + (swsum[2] + swsum[3]);
}

// ---------------- normalize: out[b,:] *= 1/sum(psum[b,:])
__global__ __launch_bounds__(256) void norm_kernel(float* __restrict__ out,
                                                   const float* __restrict__ psum)
{
  int b = blockIdx.x, tid = threadIdx.x;
  float s = 0.f;
  #pragma unroll
  for (int p = 0; p < 16; ++p) s += psum[b * 16 + p];
  float inv = 1.f / s;
  float4* row = (float4*)(out + (size_t)b * T_);
  #pragma unroll
  for (int j = 0; j < 2; ++j) {
    float4 x = row[tid + j * 256];
    x.x *= inv; x.y *= inv; x.z *= inv; x.w *= inv;
    row[tid + j * 256] = x;
  }
}

extern "C" void kernel_launch(void* const* d_in, const int* in_sizes, int n_in,
                              void* d_out, int out_size, void* d_ws, size_t ws_size,
                              hipStream_t stream)
{
  const float* enc   = (const float*)d_in[0];
  const float* dh    = (const float*)d_in[1];
  const float* prev  = (const float*)d_in[2];
  const float* Wq    = (const float*)d_in[3];
  const float* Wk    = (const float*)d_in[4];
  const float* convw = (const float*)d_in[5];
  const float* convb = (const float*)d_in[6];
  const float* Wloc  = (const float*)d_in[7];
  const float* v     = (const float*)d_in[8];
  float* out = (float*)d_out;

  char* w = (char*)d_ws;
  unsigned short* wkf   = (unsigned short*)w;               // 16 slices x 8 KB = 131072 B
  unsigned short* wlocf = (unsigned short*)(w + 131072);    // slice 16, 8192 B (contiguous!)
  float*          q2p   = (float*)(w + 139264);             // 8*64*128 f32 = 262144 B
  float*          psum  = (float*)(w + 401408);             // 64*16 f32 = 4096 B

  hipLaunchKernelGGL(prep_kernel, dim3(546), dim3(256), 0, stream,
                     dh, Wq, convb, Wloc, Wk, wkf, wlocf, q2p);
  hipLaunchKernelGGL(energy_kernel, dim3(1024), dim3(256), 0, stream,
                     enc, prev, convw, wkf, q2p, v, out, psum);
  hipLaunchKernelGGL(norm_kernel, dim3(64), dim3(256), 0, stream, out, psum);
}